// Round 3
// baseline (154.895 us; speedup 1.0000x reference)
//
#include <hip/hip_runtime.h>

// CapsuleLayer fused: priors GEMM + dynamic routing in ONE kernel.
// Shapes: x (4,256,14,14), W (32,288,8,16), out (4,512,12,12).
// Block = (o, 6 consecutive ow at one (b,oh)). 384 threads = 6 waves.
// Phase 0: stage x footprint (3 rows x 8 cols x 256 ch) in LDS, swizzled.
// Phase 1: priors, thread = (cg, kg in [0,96)), k = kg + 96*chunk; weight
//          quad loaded once per (k,cg), amortized over 6 n.
// Handoff: P in 3 LDS chunks of 6 slabs; write/read addr = base + lane.
// Phase 2: wave = one n; routing fully intra-wave (k-reduce strides 4..32,
//          c-reduce strides 1,2).
static constexpr int NSP = 144;

__device__ __forceinline__ void fma4(float4& a, float s, const float4& w) {
    a.x = fmaf(s, w.x, a.x);
    a.y = fmaf(s, w.y, a.y);
    a.z = fmaf(s, w.z, a.z);
    a.w = fmaf(s, w.w, a.w);
}

__device__ __forceinline__ float4 shfl_xor4(const float4& v, int m) {
    float4 r;
    r.x = __shfl_xor(v.x, m);
    r.y = __shfl_xor(v.y, m);
    r.z = __shfl_xor(v.z, m);
    r.w = __shfl_xor(v.w, m);
    return r;
}

__global__ __launch_bounds__(384, 3)
void caps_fused(const float* __restrict__ x, const float4* __restrict__ W4,
                float* __restrict__ out) {
    // x tile: [sp][icS] stride 12 floats (pad 4 keeps b128 alignment;
    // 12*ic mod 32 has period 8 -> exactly 2-way on phase-1 reads = free).
    // icS = (ic + sp) & 31 swizzle spreads the fill-write banks.
    __shared__ float  Xl[24 * 32 * 12];     // 36,864 B
    __shared__ float4 Pl[6 * 6 * 64];       // 36,864 B  (73.7 KB total -> 2 blk/CU)

    const int tid = threadIdx.x;
    const int o   = blockIdx.y;
    const int bx  = blockIdx.x;             // [0,96)
    const int b   = bx / 24;
    const int r24 = bx - b * 24;
    const int oh  = r24 >> 1;
    const int ow0 = (r24 & 1) * 6;

    const int cg   = tid & 3;
    const int kg   = tid >> 2;              // [0,96)
    const int wv   = tid >> 6;              // [0,6)
    const int lane = tid & 63;

    // ---------------- phase 0: stage x tile ----------------
    {
        const float* xb = x + (size_t)b * (256 * 196) + oh * 14 + ow0;
        #pragma unroll
        for (int it = 0; it < 16; ++it) {
            const int e  = it * 384 + tid;  // e = ch*24 + sp, e < 6144
            const int ch = e / 24;
            const int sp = e - ch * 24;
            const int r  = sp >> 3, c = sp & 7;
            const int ic = ch >> 3, i = ch & 7;
            const int icS = (ic + sp) & 31;
            Xl[(sp * 32 + icS) * 12 + i] = xb[ch * 196 + r * 14 + c];
        }
    }
    __syncthreads();

    const float4* X4 = (const float4*)Xl;
    float4 P[18];

    // ---------------- phase 1: priors in 3 chunks ----------------
    #pragma unroll
    for (int cch = 0; cch < 3; ++cch) {
        const int k  = kg + 96 * cch;       // [0,288)
        const int ic = k & 31;
        const int kk = k >> 5;              // uniform per wave
        const int kh = kk / 3, kw = kk - kh * 3;

        float4 w[8];
        const float4* wp = W4 + ((size_t)(o * 288 + k) * 8) * 4 + cg;
        #pragma unroll
        for (int i = 0; i < 8; ++i) w[i] = wp[i * 4];

        #pragma unroll
        for (int nn = 0; nn < 6; ++nn) {
            const int sp  = kh * 8 + nn + kw;
            const int icS = (ic + sp) & 31;
            const int b4  = (sp * 32 + icS) * 3;
            const float4 t0 = X4[b4];
            const float4 t1 = X4[b4 + 1];
            float4 a = make_float4(0.f, 0.f, 0.f, 0.f);
            fma4(a, t0.x, w[0]); fma4(a, t0.y, w[1]);
            fma4(a, t0.z, w[2]); fma4(a, t0.w, w[3]);
            fma4(a, t1.x, w[4]); fma4(a, t1.y, w[5]);
            fma4(a, t1.z, w[6]); fma4(a, t1.w, w[7]);
            // jjl = kg>>4 = wv; (kg&15)*4 + cg = lane  -> addr = base + lane
            Pl[nn * 384 + wv * 64 + lane] = a;
        }
        __syncthreads();
        #pragma unroll
        for (int jjl = 0; jjl < 6; ++jjl)
            P[cch * 6 + jjl] = Pl[wv * 384 + jjl * 64 + lane];
        if (cch < 2) __syncthreads();
    }

    // ---------------- phase 2: dynamic routing (wave = n) ----------------
    float lj[18];
    #pragma unroll
    for (int jj = 0; jj < 18; ++jj) lj[jj] = 0.f;
    float4 vq = make_float4(0.f, 0.f, 0.f, 0.f);

    #pragma unroll
    for (int it = 0; it < 3; ++it) {
        float4 svU = make_float4(0.f, 0.f, 0.f, 0.f);
        float S;
        if (it == 0) {
            #pragma unroll
            for (int jj = 0; jj < 18; ++jj) {
                svU.x += P[jj].x; svU.y += P[jj].y;
                svU.z += P[jj].z; svU.w += P[jj].w;
            }
            #pragma unroll
            for (int m = 4; m < 64; m <<= 1) {
                const float4 t = shfl_xor4(svU, m);
                svU.x += t.x; svU.y += t.y; svU.z += t.z; svU.w += t.w;
            }
            S = 288.0f;
        } else {
            S = 0.f;
            #pragma unroll
            for (int jj = 0; jj < 18; ++jj) {
                const float e = __expf(lj[jj]);   // |lj| <~ 10, safe w/o max
                S += e;
                fma4(svU, e, P[jj]);
            }
            #pragma unroll
            for (int m = 4; m < 64; m <<= 1) {
                const float4 t = shfl_xor4(svU, m);
                svU.x += t.x; svU.y += t.y; svU.z += t.z; svU.w += t.w;
                S += __shfl_xor(S, m);
            }
        }
        const float invS = __frcp_rn(S);
        float4 s;
        s.x = svU.x * invS; s.y = svU.y * invS;
        s.z = svU.z * invS; s.w = svU.w * invS;
        float sq = s.x * s.x + s.y * s.y + s.z * s.z + s.w * s.w;
        sq += __shfl_xor(sq, 1);
        sq += __shfl_xor(sq, 2);
        const float scale = __fsqrt_rn(sq) / (1.0f + sq);
        vq.x = s.x * scale; vq.y = s.y * scale;
        vq.z = s.z * scale; vq.w = s.w * scale;

        if (it < 2) {
            #pragma unroll
            for (int jj = 0; jj < 18; ++jj) {
                float d = P[jj].x * vq.x + P[jj].y * vq.y +
                          P[jj].z * vq.z + P[jj].w * vq.w;
                d += __shfl_xor(d, 1);
                d += __shfl_xor(d, 2);
                lj[jj] += d;
            }
        }
    }

    // ---------------- store: lanes 0..3 (kgp==0) write their c-quad ----------------
    if ((lane >> 2) == 0) {
        const int rm = oh * 12 + ow0 + wv;
        float* op = out + (size_t)(b * 512 + o * 16 + cg * 4) * NSP + rm;
        op[0 * NSP] = vq.x;
        op[1 * NSP] = vq.y;
        op[2 * NSP] = vq.z;
        op[3 * NSP] = vq.w;
    }
}

extern "C" void kernel_launch(void* const* d_in, const int* in_sizes, int n_in,
                              void* d_out, int out_size, void* d_ws, size_t ws_size,
                              hipStream_t stream) {
    const float* x  = (const float*)d_in[0];   // (4, 256, 14, 14)
    const float* wt = (const float*)d_in[1];   // (32, 288, 8, 16)
    float* out = (float*)d_out;                // (4, 512, 12, 12)
    (void)d_ws; (void)ws_size;

    caps_fused<<<dim3(96, 32), 384, 0, stream>>>(x, (const float4*)wt, out);
}